// Round 1
// baseline (321.135 us; speedup 1.0000x reference)
//
#include <hip/hip_runtime.h>
#include <hip/hip_bf16.h>
#include <math.h>

#define T_TOK 2048
#define DIM   1024
#define NEXP  16
#define FDIM  512
#define TOPK  2

#define BM 128
#define BN 128
#define BK 32

typedef float f32x4 __attribute__((ext_vector_type(4)));
typedef short s16x8 __attribute__((ext_vector_type(8)));

static __device__ __forceinline__ ushort f2bf(float f) {
  union { float f; unsigned u; } v; v.f = f;
  unsigned u = v.u;
  unsigned r = u + 0x7fffu + ((u >> 16) & 1u);  // round-to-nearest-even
  return (ushort)(r >> 16);
}
static __device__ __forceinline__ float bf2f(ushort h) {
  union { unsigned u; float f; } v; v.u = ((unsigned)h) << 16; return v.f;
}
static __device__ __forceinline__ void split2(float f, ushort& h, ushort& l) {
  ushort hb = f2bf(f);
  h = hb;
  l = f2bf(f - bf2f(hb));
}

// ---------------- Router: logits -> top-2 -> renormalized weights ----------
__global__ __launch_bounds__(64) void router_k(const float* __restrict__ x,
                                               const float* __restrict__ wg,
                                               int* __restrict__ sel,
                                               float* __restrict__ wt,
                                               int* __restrict__ cnt) {
  int t = blockIdx.x;
  int lane = threadIdx.x;
  const float* xr = x + (size_t)t * DIM;
  float acc[NEXP];
#pragma unroll
  for (int e = 0; e < NEXP; ++e) acc[e] = 0.f;
  for (int d0 = 0; d0 < DIM; d0 += 64) {
    float xv = xr[d0 + lane];
#pragma unroll
    for (int e = 0; e < NEXP; ++e) acc[e] += xv * wg[e * DIM + d0 + lane];
  }
#pragma unroll
  for (int e = 0; e < NEXP; ++e) {
    float v = acc[e];
    v += __shfl_xor(v, 32); v += __shfl_xor(v, 16); v += __shfl_xor(v, 8);
    v += __shfl_xor(v, 4);  v += __shfl_xor(v, 2);  v += __shfl_xor(v, 1);
    acc[e] = v;
  }
  if (lane == 0) {
    float b1 = -1e30f, b2 = -1e30f; int i1 = 0, i2 = 0;
#pragma unroll
    for (int e = 0; e < NEXP; ++e) {
      float v = acc[e];
      if (v > b1) { b2 = b1; i2 = i1; b1 = v; i1 = e; }
      else if (v > b2) { b2 = v; i2 = e; }
    }
    // NORM_TOPK: softmax denominator cancels -> w1 = 1/(1+exp(l2-l1))
    float r = expf(b2 - b1);
    float w2v = r / (1.f + r);
    float w1v = 1.f - w2v;
    sel[t * 2 + 0] = i1; sel[t * 2 + 1] = i2;
    wt[t * 2 + 0] = w1v; wt[t * 2 + 1] = w2v;
    atomicAdd(&cnt[i1], 1);
    atomicAdd(&cnt[i2], 1);
  }
}

// ---------------- X -> bf16 hi/lo planes -----------------------------------
__global__ __launch_bounds__(256) void xsplit_k(const float* __restrict__ x,
                                                ushort* __restrict__ xhi,
                                                ushort* __restrict__ xlo) {
  int idx = (blockIdx.x * 256 + threadIdx.x) * 4;
  float4 v = *(const float4*)(x + idx);
  ushort h0,h1,h2,h3,l0,l1,l2,l3;
  split2(v.x, h0, l0); split2(v.y, h1, l1);
  split2(v.z, h2, l2); split2(v.w, h3, l3);
  *(ushort4*)(xhi + idx) = make_ushort4(h0, h1, h2, h3);
  *(ushort4*)(xlo + idx) = make_ushort4(l0, l1, l2, l3);
}

// ---------------- exclusive prefix over expert counts ----------------------
__global__ void offsets_k(const int* __restrict__ cnt, int* __restrict__ off) {
  if (threadIdx.x == 0 && blockIdx.x == 0) {
    int s = 0;
#pragma unroll
    for (int e = 0; e < NEXP; ++e) { off[e] = s; s += cnt[e]; }
    off[NEXP] = s;  // == T_TOK*TOPK
  }
}

// ---------------- compact (token, weight) rows per expert ------------------
__global__ __launch_bounds__(256) void fill_k(const int* __restrict__ sel,
                                              const float* __restrict__ wt,
                                              const int* __restrict__ off,
                                              int* __restrict__ cnt2,
                                              int* __restrict__ rowtok,
                                              float* __restrict__ rowwt) {
  int i = blockIdx.x * 256 + threadIdx.x;
  if (i >= T_TOK * TOPK) return;
  int e = sel[i];
  int pos = off[e] + atomicAdd(&cnt2[e], 1);
  rowtok[pos] = i >> 1;
  rowwt[pos] = wt[i];
}

// ---------------- GEMM1: H[r][c] = sum_d X[tok(r)][d] * W13[e][c][d] -------
__global__ __launch_bounds__(256, 2) void gemm1_k(const ushort* __restrict__ xhi,
                                                  const ushort* __restrict__ xlo,
                                                  const float* __restrict__ w13,
                                                  const int* __restrict__ off,
                                                  const int* __restrict__ rowtok,
                                                  float* __restrict__ H) {
  int e = blockIdx.z;
  int rbeg = off[e];
  int rows = off[e + 1] - rbeg;
  int m0 = blockIdx.y * BM;
  if (m0 >= rows) return;
  int n0 = blockIdx.x * BN;

  __shared__ ushort Ah[BM * BK], Al[BM * BK], Bh[BN * BK], Bl[BN * BK];
  __shared__ int toksh[BM];

  int tid = threadIdx.x;
  if (tid < BM) {
    int r = m0 + tid;
    toksh[tid] = rowtok[rbeg + (r < rows ? r : 0)];
  }
  __syncthreads();

  f32x4 acc[4][4];
#pragma unroll
  for (int a = 0; a < 4; ++a)
#pragma unroll
    for (int b = 0; b < 4; ++b) acc[a][b] = {0.f, 0.f, 0.f, 0.f};

  int lane = tid & 63;
  int w = tid >> 6;
  int wm = (w & 1) * 64, wn = (w >> 1) * 64;
  int lr = lane & 15, lk = lane >> 4;
  int srow = tid >> 2;   // staging row 0..63
  int sc = tid & 3;      // staging k-chunk (8 elems)

  for (int kb = 0; kb < DIM; kb += BK) {
    // A staging: gathered bf16 hi/lo rows
#pragma unroll
    for (int h = 0; h < 2; ++h) {
      int row = srow + h * 64;
      int tok = toksh[row];
      uint4 vh = *(const uint4*)(xhi + (size_t)tok * DIM + kb + sc * 8);
      uint4 vl = *(const uint4*)(xlo + (size_t)tok * DIM + kb + sc * 8);
      int bo = (row * (BK * 2) + sc * 16) ^ ((row & 7) << 4);
      *(uint4*)((char*)Ah + bo) = vh;
      *(uint4*)((char*)Al + bo) = vl;
    }
    // B staging: fp32 -> hi/lo bf16 conversion in-flight
#pragma unroll
    for (int h = 0; h < 2; ++h) {
      int row = srow + h * 64;
      const float* src = w13 + ((size_t)e * (2 * FDIM) + (n0 + row)) * DIM + kb + sc * 8;
      float4 f0 = *(const float4*)src;
      float4 f1 = *(const float4*)(src + 4);
      float fv[8] = {f0.x, f0.y, f0.z, f0.w, f1.x, f1.y, f1.z, f1.w};
      uint hp[4], lp[4];
#pragma unroll
      for (int j = 0; j < 4; ++j) {
        ushort ha, la, hb, lb;
        split2(fv[2 * j], ha, la);
        split2(fv[2 * j + 1], hb, lb);
        hp[j] = (uint)ha | ((uint)hb << 16);
        lp[j] = (uint)la | ((uint)lb << 16);
      }
      int bo = (row * (BK * 2) + sc * 16) ^ ((row & 7) << 4);
      *(uint4*)((char*)Bh + bo) = make_uint4(hp[0], hp[1], hp[2], hp[3]);
      *(uint4*)((char*)Bl + bo) = make_uint4(lp[0], lp[1], lp[2], lp[3]);
    }
    __syncthreads();

    s16x8 ah[4], al[4], bh[4], bl[4];
#pragma unroll
    for (int fm = 0; fm < 4; ++fm) {
      int row = wm + fm * 16 + lr;
      int bo = (row * 64 + lk * 16) ^ ((row & 7) << 4);
      ah[fm] = *(const s16x8*)((char*)Ah + bo);
      al[fm] = *(const s16x8*)((char*)Al + bo);
    }
#pragma unroll
    for (int fn = 0; fn < 4; ++fn) {
      int row = wn + fn * 16 + lr;
      int bo = (row * 64 + lk * 16) ^ ((row & 7) << 4);
      bh[fn] = *(const s16x8*)((char*)Bh + bo);
      bl[fn] = *(const s16x8*)((char*)Bl + bo);
    }
#pragma unroll
    for (int fm = 0; fm < 4; ++fm)
#pragma unroll
      for (int fn = 0; fn < 4; ++fn) {
        acc[fm][fn] = __builtin_amdgcn_mfma_f32_16x16x32_bf16(ah[fm], bh[fn], acc[fm][fn], 0, 0, 0);
        acc[fm][fn] = __builtin_amdgcn_mfma_f32_16x16x32_bf16(ah[fm], bl[fn], acc[fm][fn], 0, 0, 0);
        acc[fm][fn] = __builtin_amdgcn_mfma_f32_16x16x32_bf16(al[fm], bh[fn], acc[fm][fn], 0, 0, 0);
      }
    __syncthreads();
  }

  // epilogue: C/D layout col=lane&15, row=(lane>>4)*4+j  [m89/m91 verified]
#pragma unroll
  for (int fm = 0; fm < 4; ++fm) {
    int rloc = wm + fm * 16 + lk * 4;
#pragma unroll
    for (int j = 0; j < 4; ++j) {
      int row = rloc + j;
      if (m0 + row < rows) {
        size_t gr = (size_t)(rbeg + m0 + row) * (2 * FDIM);
#pragma unroll
        for (int fn = 0; fn < 4; ++fn)
          H[gr + n0 + wn + fn * 16 + lr] = acc[fm][fn][j];
      }
    }
  }
}

// ---------------- act = silu(gate)*up, stored as bf16 hi/lo ----------------
__global__ __launch_bounds__(256) void act_k(const float* __restrict__ H,
                                             ushort* __restrict__ ahi,
                                             ushort* __restrict__ alo) {
  int idx = (blockIdx.x * 256 + threadIdx.x) * 4;  // over 4096*512
  int r = idx >> 9;
  int f = idx & 511;
  const float* hrow = H + (size_t)r * (2 * FDIM);
  float4 g = *(const float4*)(hrow + f);
  float4 u = *(const float4*)(hrow + FDIM + f);
  float a0 = g.x / (1.f + expf(-g.x)) * u.x;
  float a1 = g.y / (1.f + expf(-g.y)) * u.y;
  float a2 = g.z / (1.f + expf(-g.z)) * u.z;
  float a3 = g.w / (1.f + expf(-g.w)) * u.w;
  ushort h0,h1,h2,h3,l0,l1,l2,l3;
  split2(a0, h0, l0); split2(a1, h1, l1);
  split2(a2, h2, l2); split2(a3, h3, l3);
  *(ushort4*)(ahi + (size_t)r * FDIM + f) = make_ushort4(h0, h1, h2, h3);
  *(ushort4*)(alo + (size_t)r * FDIM + f) = make_ushort4(l0, l1, l2, l3);
}

// ---------------- GEMM2: out[tok(r)][d] += w(r) * sum_f act[r][f]*W2[e][d][f]
__global__ __launch_bounds__(256, 2) void gemm2_k(const ushort* __restrict__ ahi,
                                                  const ushort* __restrict__ alo,
                                                  const float* __restrict__ w2,
                                                  const int* __restrict__ off,
                                                  const int* __restrict__ rowtok,
                                                  const float* __restrict__ rowwt,
                                                  float* __restrict__ out) {
  int e = blockIdx.z;
  int rbeg = off[e];
  int rows = off[e + 1] - rbeg;
  int m0 = blockIdx.y * BM;
  if (m0 >= rows) return;
  int n0 = blockIdx.x * BN;

  __shared__ ushort Ah[BM * BK], Al[BM * BK], Bh[BN * BK], Bl[BN * BK];
  __shared__ int toksh[BM];
  __shared__ float wtsh[BM];

  int tid = threadIdx.x;
  if (tid < BM) {
    int r = m0 + tid;
    int rr = rbeg + (r < rows ? r : 0);
    toksh[tid] = rowtok[rr];
    wtsh[tid] = (r < rows) ? rowwt[rr] : 0.f;
  }
  __syncthreads();

  f32x4 acc[4][4];
#pragma unroll
  for (int a = 0; a < 4; ++a)
#pragma unroll
    for (int b = 0; b < 4; ++b) acc[a][b] = {0.f, 0.f, 0.f, 0.f};

  int lane = tid & 63;
  int w = tid >> 6;
  int wm = (w & 1) * 64, wn = (w >> 1) * 64;
  int lr = lane & 15, lk = lane >> 4;
  int srow = tid >> 2;
  int sc = tid & 3;

  for (int kb = 0; kb < FDIM; kb += BK) {
    // A staging: compact act rows (no gather), clamp to stay in-bounds
#pragma unroll
    for (int h = 0; h < 2; ++h) {
      int row = srow + h * 64;
      int rg = m0 + row; rg = (rg < rows ? rg : rows - 1);
      size_t srcr = (size_t)(rbeg + rg) * FDIM + kb + sc * 8;
      uint4 vh = *(const uint4*)(ahi + srcr);
      uint4 vl = *(const uint4*)(alo + srcr);
      int bo = (row * (BK * 2) + sc * 16) ^ ((row & 7) << 4);
      *(uint4*)((char*)Ah + bo) = vh;
      *(uint4*)((char*)Al + bo) = vl;
    }
    // B staging: W2[e][d][f], rows are d, K is f (contiguous)
#pragma unroll
    for (int h = 0; h < 2; ++h) {
      int row = srow + h * 64;
      const float* src = w2 + ((size_t)e * DIM + (n0 + row)) * FDIM + kb + sc * 8;
      float4 f0 = *(const float4*)src;
      float4 f1 = *(const float4*)(src + 4);
      float fv[8] = {f0.x, f0.y, f0.z, f0.w, f1.x, f1.y, f1.z, f1.w};
      uint hp[4], lp[4];
#pragma unroll
      for (int j = 0; j < 4; ++j) {
        ushort ha, la, hb, lb;
        split2(fv[2 * j], ha, la);
        split2(fv[2 * j + 1], hb, lb);
        hp[j] = (uint)ha | ((uint)hb << 16);
        lp[j] = (uint)la | ((uint)lb << 16);
      }
      int bo = (row * (BK * 2) + sc * 16) ^ ((row & 7) << 4);
      *(uint4*)((char*)Bh + bo) = make_uint4(hp[0], hp[1], hp[2], hp[3]);
      *(uint4*)((char*)Bl + bo) = make_uint4(lp[0], lp[1], lp[2], lp[3]);
    }
    __syncthreads();

    s16x8 ah[4], al[4], bh[4], bl[4];
#pragma unroll
    for (int fm = 0; fm < 4; ++fm) {
      int row = wm + fm * 16 + lr;
      int bo = (row * 64 + lk * 16) ^ ((row & 7) << 4);
      ah[fm] = *(const s16x8*)((char*)Ah + bo);
      al[fm] = *(const s16x8*)((char*)Al + bo);
    }
#pragma unroll
    for (int fn = 0; fn < 4; ++fn) {
      int row = wn + fn * 16 + lr;
      int bo = (row * 64 + lk * 16) ^ ((row & 7) << 4);
      bh[fn] = *(const s16x8*)((char*)Bh + bo);
      bl[fn] = *(const s16x8*)((char*)Bl + bo);
    }
#pragma unroll
    for (int fm = 0; fm < 4; ++fm)
#pragma unroll
      for (int fn = 0; fn < 4; ++fn) {
        acc[fm][fn] = __builtin_amdgcn_mfma_f32_16x16x32_bf16(ah[fm], bh[fn], acc[fm][fn], 0, 0, 0);
        acc[fm][fn] = __builtin_amdgcn_mfma_f32_16x16x32_bf16(ah[fm], bl[fn], acc[fm][fn], 0, 0, 0);
        acc[fm][fn] = __builtin_amdgcn_mfma_f32_16x16x32_bf16(al[fm], bh[fn], acc[fm][fn], 0, 0, 0);
      }
    __syncthreads();
  }

#pragma unroll
  for (int fm = 0; fm < 4; ++fm) {
    int rloc = wm + fm * 16 + lk * 4;
#pragma unroll
    for (int j = 0; j < 4; ++j) {
      int row = rloc + j;
      if (m0 + row < rows) {
        int tok = toksh[row];
        float wgt = wtsh[row];
        float* orow = out + (size_t)tok * DIM + n0;
#pragma unroll
        for (int fn = 0; fn < 4; ++fn)
          atomicAdd(orow + wn + fn * 16 + lr, wgt * acc[fm][fn][j]);
      }
    }
  }
}

// ---------------------------------------------------------------------------
extern "C" void kernel_launch(void* const* d_in, const int* in_sizes, int n_in,
                              void* d_out, int out_size, void* d_ws, size_t ws_size,
                              hipStream_t stream) {
  const float* x   = (const float*)d_in[0];
  const float* wg  = (const float*)d_in[1];
  const float* w13 = (const float*)d_in[2];
  const float* w2  = (const float*)d_in[3];
  float* out = (float*)d_out;

  char* ws = (char*)d_ws;
  int*   cnt    = (int*)(ws + 0);
  int*   cnt2   = (int*)(ws + 64);
  int*   off    = (int*)(ws + 128);
  int*   sel    = (int*)(ws + 1024);
  float* wt     = (float*)(ws + 1024 + 16384);
  int*   rowtok = (int*)(ws + 1024 + 32768);
  float* rowwt  = (float*)(ws + 1024 + 49152);
  size_t o = 128 * 1024;
  ushort* xhi = (ushort*)(ws + o); o += (size_t)T_TOK * DIM * 2;
  ushort* xlo = (ushort*)(ws + o); o += (size_t)T_TOK * DIM * 2;
  float*  H   = (float*)(ws + o);  o += (size_t)T_TOK * TOPK * 2 * FDIM * 4;
  ushort* ahi = (ushort*)(ws + o); o += (size_t)T_TOK * TOPK * FDIM * 2;
  ushort* alo = (ushort*)(ws + o); o += (size_t)T_TOK * TOPK * FDIM * 2;
  // total ws use ≈ 32.1 MB

  hipMemsetAsync(ws, 0, 256, stream);                              // cnt, cnt2
  hipMemsetAsync(d_out, 0, (size_t)out_size * sizeof(float), stream);

  router_k<<<T_TOK, 64, 0, stream>>>(x, wg, sel, wt, cnt);
  xsplit_k<<<(T_TOK * DIM) / 1024, 256, 0, stream>>>(x, xhi, xlo);
  offsets_k<<<1, 64, 0, stream>>>(cnt, off);
  fill_k<<<(T_TOK * TOPK + 255) / 256, 256, 0, stream>>>(sel, wt, off, cnt2, rowtok, rowwt);

  dim3 g1(2 * FDIM / BN, T_TOK / BM, NEXP);  // (8,16,16), most blocks early-exit
  gemm1_k<<<g1, 256, 0, stream>>>(xhi, xlo, w13, off, rowtok, H);

  act_k<<<(T_TOK * TOPK * FDIM) / 1024, 256, 0, stream>>>(H, ahi, alo);

  dim3 g2(DIM / BN, T_TOK / BM, NEXP);       // (8,16,16)
  gemm2_k<<<g2, 256, 0, stream>>>(ahi, alo, w2, off, rowtok, rowwt, out);
}

// Round 2
// 313.865 us; speedup vs baseline: 1.0232x; 1.0232x over previous
//
#include <hip/hip_runtime.h>
#include <hip/hip_bf16.h>
#include <math.h>

#define T_TOK 2048
#define DIM   1024
#define NEXP  16
#define FDIM  512
#define TOPK  2

#define BM 128
#define BN 64
#define BK 32

typedef float f32x4 __attribute__((ext_vector_type(4)));
typedef short s16x8 __attribute__((ext_vector_type(8)));

static __device__ __forceinline__ ushort f2bf(float f) {
  union { float f; unsigned u; } v; v.f = f;
  unsigned u = v.u;
  unsigned r = u + 0x7fffu + ((u >> 16) & 1u);  // round-to-nearest-even
  return (ushort)(r >> 16);
}
static __device__ __forceinline__ float bf2f(ushort h) {
  union { unsigned u; float f; } v; v.u = ((unsigned)h) << 16; return v.f;
}
static __device__ __forceinline__ void split2(float f, ushort& h, ushort& l) {
  ushort hb = f2bf(f);
  h = hb;
  l = f2bf(f - bf2f(hb));
}

// ---------------- Router: logits -> top-2 -> renormalized weights ----------
__global__ __launch_bounds__(64) void router_k(const float* __restrict__ x,
                                               const float* __restrict__ wg,
                                               int* __restrict__ sel,
                                               float* __restrict__ wt,
                                               int* __restrict__ cnt) {
  int t = blockIdx.x;
  int lane = threadIdx.x;
  const float* xr = x + (size_t)t * DIM;
  float acc[NEXP];
#pragma unroll
  for (int e = 0; e < NEXP; ++e) acc[e] = 0.f;
  for (int d0 = 0; d0 < DIM; d0 += 64) {
    float xv = xr[d0 + lane];
#pragma unroll
    for (int e = 0; e < NEXP; ++e) acc[e] += xv * wg[e * DIM + d0 + lane];
  }
#pragma unroll
  for (int e = 0; e < NEXP; ++e) {
    float v = acc[e];
    v += __shfl_xor(v, 32); v += __shfl_xor(v, 16); v += __shfl_xor(v, 8);
    v += __shfl_xor(v, 4);  v += __shfl_xor(v, 2);  v += __shfl_xor(v, 1);
    acc[e] = v;
  }
  if (lane == 0) {
    float b1 = -1e30f, b2 = -1e30f; int i1 = 0, i2 = 0;
#pragma unroll
    for (int e = 0; e < NEXP; ++e) {
      float v = acc[e];
      if (v > b1) { b2 = b1; i2 = i1; b1 = v; i1 = e; }
      else if (v > b2) { b2 = v; i2 = e; }
    }
    // NORM_TOPK: softmax denominator cancels -> w1 = 1/(1+exp(l2-l1))
    float r = expf(b2 - b1);
    float w2v = r / (1.f + r);
    float w1v = 1.f - w2v;
    sel[t * 2 + 0] = i1; sel[t * 2 + 1] = i2;
    wt[t * 2 + 0] = w1v; wt[t * 2 + 1] = w2v;
    atomicAdd(&cnt[i1], 1);
    atomicAdd(&cnt[i2], 1);
  }
}

// ---------------- X -> bf16 hi/lo planes -----------------------------------
__global__ __launch_bounds__(256) void xsplit_k(const float* __restrict__ x,
                                                ushort* __restrict__ xhi,
                                                ushort* __restrict__ xlo) {
  int idx = (blockIdx.x * 256 + threadIdx.x) * 4;
  float4 v = *(const float4*)(x + idx);
  ushort h0,h1,h2,h3,l0,l1,l2,l3;
  split2(v.x, h0, l0); split2(v.y, h1, l1);
  split2(v.z, h2, l2); split2(v.w, h3, l3);
  *(ushort4*)(xhi + idx) = make_ushort4(h0, h1, h2, h3);
  *(ushort4*)(xlo + idx) = make_ushort4(l0, l1, l2, l3);
}

// ---------------- exclusive prefix over expert counts ----------------------
__global__ void offsets_k(const int* __restrict__ cnt, int* __restrict__ off) {
  if (threadIdx.x == 0 && blockIdx.x == 0) {
    int s = 0;
#pragma unroll
    for (int e = 0; e < NEXP; ++e) { off[e] = s; s += cnt[e]; }
    off[NEXP] = s;  // == T_TOK*TOPK
  }
}

// ---------------- compact (token, weight) rows per expert ------------------
__global__ __launch_bounds__(256) void fill_k(const int* __restrict__ sel,
                                              const float* __restrict__ wt,
                                              const int* __restrict__ off,
                                              int* __restrict__ cnt2,
                                              int* __restrict__ rowtok,
                                              float* __restrict__ rowwt) {
  int i = blockIdx.x * 256 + threadIdx.x;
  if (i >= T_TOK * TOPK) return;
  int e = sel[i];
  int pos = off[e] + atomicAdd(&cnt2[e], 1);
  rowtok[pos] = i >> 1;
  rowwt[pos] = wt[i];
}

// ---------------- GEMM1: H[r][c] = sum_d X[tok(r)][d] * W13[e][c][d] -------
// BM=128, BN=64, 2x2 waves (each 64x32). T14 reg-prefetch pipeline.
__global__ __launch_bounds__(256, 2) void gemm1_k(const ushort* __restrict__ xhi,
                                                  const ushort* __restrict__ xlo,
                                                  const float* __restrict__ w13,
                                                  const int* __restrict__ off,
                                                  const int* __restrict__ rowtok,
                                                  float* __restrict__ H) {
  int e = blockIdx.z;
  int rbeg = off[e];
  int rows = off[e + 1] - rbeg;
  int m0 = blockIdx.y * BM;
  if (m0 >= rows) return;
  int n0 = blockIdx.x * BN;

  __shared__ ushort Ah[BM * BK], Al[BM * BK], Bh[BN * BK], Bl[BN * BK];
  __shared__ int toksh[BM];

  int tid = threadIdx.x;
  if (tid < BM) {
    int r = m0 + tid;
    toksh[tid] = rowtok[rbeg + (r < rows ? r : rows - 1)];
  }
  __syncthreads();

  int srow = tid >> 2;   // 0..63
  int sc = tid & 3;      // k-chunk of 8 elems
  int tok0 = toksh[srow];
  int tok1 = toksh[srow + 64];
  const ushort* a0h = xhi + (size_t)tok0 * DIM + sc * 8;
  const ushort* a0l = xlo + (size_t)tok0 * DIM + sc * 8;
  const ushort* a1h = xhi + (size_t)tok1 * DIM + sc * 8;
  const ushort* a1l = xlo + (size_t)tok1 * DIM + sc * 8;
  const float*  bsrc = w13 + ((size_t)e * (2 * FDIM) + (n0 + srow)) * DIM + sc * 8;

  // swizzled staging byte offsets (row stride 64B, XOR bits 4-6 with row&7)
  int boA0 = (srow * 64 + sc * 16) ^ ((srow & 7) << 4);
  int boA1 = ((srow + 64) * 64 + sc * 16) ^ ((srow & 7) << 4);
  int boB  = boA0;

  f32x4 acc[4][2];
#pragma unroll
  for (int a = 0; a < 4; ++a)
#pragma unroll
    for (int b = 0; b < 2; ++b) acc[a][b] = {0.f, 0.f, 0.f, 0.f};

  int lane = tid & 63;
  int w = tid >> 6;
  int wm = (w & 1) * 64, wn = (w >> 1) * 32;
  int lr = lane & 15, lk = lane >> 4;

  // prefetch registers
  uint4 rA0h, rA0l, rA1h, rA1l;
  float4 rB0, rB1;

  // prologue: issue k-step 0 loads
  rA0h = *(const uint4*)(a0h); rA0l = *(const uint4*)(a0l);
  rA1h = *(const uint4*)(a1h); rA1l = *(const uint4*)(a1l);
  rB0 = *(const float4*)(bsrc); rB1 = *(const float4*)(bsrc + 4);

  const int NS = DIM / BK;
  for (int ks = 0; ks < NS; ++ks) {
    __syncthreads();  // prev MFMA done reading LDS
    // write phase (conversion off the load critical path)
    *(uint4*)((char*)Ah + boA0) = rA0h;
    *(uint4*)((char*)Al + boA0) = rA0l;
    *(uint4*)((char*)Ah + boA1) = rA1h;
    *(uint4*)((char*)Al + boA1) = rA1l;
    {
      float fv[8] = {rB0.x, rB0.y, rB0.z, rB0.w, rB1.x, rB1.y, rB1.z, rB1.w};
      uint hp[4], lp[4];
#pragma unroll
      for (int j = 0; j < 4; ++j) {
        ushort ha, la, hb, lb;
        split2(fv[2 * j], ha, la);
        split2(fv[2 * j + 1], hb, lb);
        hp[j] = (uint)ha | ((uint)hb << 16);
        lp[j] = (uint)la | ((uint)lb << 16);
      }
      *(uint4*)((char*)Bh + boB) = make_uint4(hp[0], hp[1], hp[2], hp[3]);
      *(uint4*)((char*)Bl + boB) = make_uint4(lp[0], lp[1], lp[2], lp[3]);
    }
    // issue next k-step loads early: latency hides under barrier+ds_read+MFMA
    if (ks + 1 < NS) {
      int kb = (ks + 1) * BK;
      rA0h = *(const uint4*)(a0h + kb); rA0l = *(const uint4*)(a0l + kb);
      rA1h = *(const uint4*)(a1h + kb); rA1l = *(const uint4*)(a1l + kb);
      rB0 = *(const float4*)(bsrc + kb); rB1 = *(const float4*)(bsrc + kb + 4);
    }
    __syncthreads();  // LDS visible

    s16x8 ah[4], al[4], bh[2], bl[2];
#pragma unroll
    for (int fm = 0; fm < 4; ++fm) {
      int row = wm + fm * 16 + lr;
      int bo = (row * 64 + lk * 16) ^ ((row & 7) << 4);
      ah[fm] = *(const s16x8*)((char*)Ah + bo);
      al[fm] = *(const s16x8*)((char*)Al + bo);
    }
#pragma unroll
    for (int fn = 0; fn < 2; ++fn) {
      int row = wn + fn * 16 + lr;
      int bo = (row * 64 + lk * 16) ^ ((row & 7) << 4);
      bh[fn] = *(const s16x8*)((char*)Bh + bo);
      bl[fn] = *(const s16x8*)((char*)Bl + bo);
    }
#pragma unroll
    for (int fm = 0; fm < 4; ++fm)
#pragma unroll
      for (int fn = 0; fn < 2; ++fn) {
        acc[fm][fn] = __builtin_amdgcn_mfma_f32_16x16x32_bf16(ah[fm], bh[fn], acc[fm][fn], 0, 0, 0);
        acc[fm][fn] = __builtin_amdgcn_mfma_f32_16x16x32_bf16(ah[fm], bl[fn], acc[fm][fn], 0, 0, 0);
        acc[fm][fn] = __builtin_amdgcn_mfma_f32_16x16x32_bf16(al[fm], bh[fn], acc[fm][fn], 0, 0, 0);
      }
  }

  // epilogue: C/D layout col=lane&15, row=(lane>>4)*4+j  [m89/m91 verified]
#pragma unroll
  for (int fm = 0; fm < 4; ++fm) {
    int rloc = wm + fm * 16 + lk * 4;
#pragma unroll
    for (int j = 0; j < 4; ++j) {
      int row = rloc + j;
      if (m0 + row < rows) {
        size_t gr = (size_t)(rbeg + m0 + row) * (2 * FDIM);
#pragma unroll
        for (int fn = 0; fn < 2; ++fn)
          H[gr + n0 + wn + fn * 16 + lr] = acc[fm][fn][j];
      }
    }
  }
}

// ---------------- act = silu(gate)*up, stored as bf16 hi/lo ----------------
__global__ __launch_bounds__(256) void act_k(const float* __restrict__ H,
                                             ushort* __restrict__ ahi,
                                             ushort* __restrict__ alo) {
  int idx = (blockIdx.x * 256 + threadIdx.x) * 4;  // over 4096*512
  int r = idx >> 9;
  int f = idx & 511;
  const float* hrow = H + (size_t)r * (2 * FDIM);
  float4 g = *(const float4*)(hrow + f);
  float4 u = *(const float4*)(hrow + FDIM + f);
  float a0 = g.x / (1.f + expf(-g.x)) * u.x;
  float a1 = g.y / (1.f + expf(-g.y)) * u.y;
  float a2 = g.z / (1.f + expf(-g.z)) * u.z;
  float a3 = g.w / (1.f + expf(-g.w)) * u.w;
  ushort h0,h1,h2,h3,l0,l1,l2,l3;
  split2(a0, h0, l0); split2(a1, h1, l1);
  split2(a2, h2, l2); split2(a3, h3, l3);
  *(ushort4*)(ahi + (size_t)r * FDIM + f) = make_ushort4(h0, h1, h2, h3);
  *(ushort4*)(alo + (size_t)r * FDIM + f) = make_ushort4(l0, l1, l2, l3);
}

// ---------------- GEMM2: out[tok(r)][d] += w(r) * sum_f act[r][f]*W2[e][d][f]
__global__ __launch_bounds__(256, 2) void gemm2_k(const ushort* __restrict__ ahi,
                                                  const ushort* __restrict__ alo,
                                                  const float* __restrict__ w2,
                                                  const int* __restrict__ off,
                                                  const int* __restrict__ rowtok,
                                                  const float* __restrict__ rowwt,
                                                  float* __restrict__ out) {
  int e = blockIdx.z;
  int rbeg = off[e];
  int rows = off[e + 1] - rbeg;
  int m0 = blockIdx.y * BM;
  if (m0 >= rows) return;
  int n0 = blockIdx.x * BN;

  __shared__ ushort Ah[BM * BK], Al[BM * BK], Bh[BN * BK], Bl[BN * BK];
  __shared__ int toksh[BM];
  __shared__ float wtsh[BM];

  int tid = threadIdx.x;
  if (tid < BM) {
    int r = m0 + tid;
    int rr = rbeg + (r < rows ? r : rows - 1);
    toksh[tid] = rowtok[rr];
    wtsh[tid] = (r < rows) ? rowwt[rr] : 0.f;
  }
  __syncthreads();

  int srow = tid >> 2;
  int sc = tid & 3;
  int rg0 = m0 + srow;       rg0 = (rg0 < rows ? rg0 : rows - 1);
  int rg1 = m0 + srow + 64;  rg1 = (rg1 < rows ? rg1 : rows - 1);
  const ushort* a0h = ahi + (size_t)(rbeg + rg0) * FDIM + sc * 8;
  const ushort* a0l = alo + (size_t)(rbeg + rg0) * FDIM + sc * 8;
  const ushort* a1h = ahi + (size_t)(rbeg + rg1) * FDIM + sc * 8;
  const ushort* a1l = alo + (size_t)(rbeg + rg1) * FDIM + sc * 8;
  const float*  bsrc = w2 + ((size_t)e * DIM + (n0 + srow)) * FDIM + sc * 8;

  int boA0 = (srow * 64 + sc * 16) ^ ((srow & 7) << 4);
  int boA1 = ((srow + 64) * 64 + sc * 16) ^ ((srow & 7) << 4);
  int boB  = boA0;

  f32x4 acc[4][2];
#pragma unroll
  for (int a = 0; a < 4; ++a)
#pragma unroll
    for (int b = 0; b < 2; ++b) acc[a][b] = {0.f, 0.f, 0.f, 0.f};

  int lane = tid & 63;
  int w = tid >> 6;
  int wm = (w & 1) * 64, wn = (w >> 1) * 32;
  int lr = lane & 15, lk = lane >> 4;

  uint4 rA0h, rA0l, rA1h, rA1l;
  float4 rB0, rB1;
  rA0h = *(const uint4*)(a0h); rA0l = *(const uint4*)(a0l);
  rA1h = *(const uint4*)(a1h); rA1l = *(const uint4*)(a1l);
  rB0 = *(const float4*)(bsrc); rB1 = *(const float4*)(bsrc + 4);

  const int NS = FDIM / BK;
  for (int ks = 0; ks < NS; ++ks) {
    __syncthreads();
    *(uint4*)((char*)Ah + boA0) = rA0h;
    *(uint4*)((char*)Al + boA0) = rA0l;
    *(uint4*)((char*)Ah + boA1) = rA1h;
    *(uint4*)((char*)Al + boA1) = rA1l;
    {
      float fv[8] = {rB0.x, rB0.y, rB0.z, rB0.w, rB1.x, rB1.y, rB1.z, rB1.w};
      uint hp[4], lp[4];
#pragma unroll
      for (int j = 0; j < 4; ++j) {
        ushort ha, la, hb, lb;
        split2(fv[2 * j], ha, la);
        split2(fv[2 * j + 1], hb, lb);
        hp[j] = (uint)ha | ((uint)hb << 16);
        lp[j] = (uint)la | ((uint)lb << 16);
      }
      *(uint4*)((char*)Bh + boB) = make_uint4(hp[0], hp[1], hp[2], hp[3]);
      *(uint4*)((char*)Bl + boB) = make_uint4(lp[0], lp[1], lp[2], lp[3]);
    }
    if (ks + 1 < NS) {
      int kb = (ks + 1) * BK;
      rA0h = *(const uint4*)(a0h + kb); rA0l = *(const uint4*)(a0l + kb);
      rA1h = *(const uint4*)(a1h + kb); rA1l = *(const uint4*)(a1l + kb);
      rB0 = *(const float4*)(bsrc + kb); rB1 = *(const float4*)(bsrc + kb + 4);
    }
    __syncthreads();

    s16x8 ah[4], al[4], bh[2], bl[2];
#pragma unroll
    for (int fm = 0; fm < 4; ++fm) {
      int row = wm + fm * 16 + lr;
      int bo = (row * 64 + lk * 16) ^ ((row & 7) << 4);
      ah[fm] = *(const s16x8*)((char*)Ah + bo);
      al[fm] = *(const s16x8*)((char*)Al + bo);
    }
#pragma unroll
    for (int fn = 0; fn < 2; ++fn) {
      int row = wn + fn * 16 + lr;
      int bo = (row * 64 + lk * 16) ^ ((row & 7) << 4);
      bh[fn] = *(const s16x8*)((char*)Bh + bo);
      bl[fn] = *(const s16x8*)((char*)Bl + bo);
    }
#pragma unroll
    for (int fm = 0; fm < 4; ++fm)
#pragma unroll
      for (int fn = 0; fn < 2; ++fn) {
        acc[fm][fn] = __builtin_amdgcn_mfma_f32_16x16x32_bf16(ah[fm], bh[fn], acc[fm][fn], 0, 0, 0);
        acc[fm][fn] = __builtin_amdgcn_mfma_f32_16x16x32_bf16(ah[fm], bl[fn], acc[fm][fn], 0, 0, 0);
        acc[fm][fn] = __builtin_amdgcn_mfma_f32_16x16x32_bf16(al[fm], bh[fn], acc[fm][fn], 0, 0, 0);
      }
  }

#pragma unroll
  for (int fm = 0; fm < 4; ++fm) {
    int rloc = wm + fm * 16 + lk * 4;
#pragma unroll
    for (int j = 0; j < 4; ++j) {
      int row = rloc + j;
      if (m0 + row < rows) {
        int tok = toksh[row];
        float wgt = wtsh[row];
        float* orow = out + (size_t)tok * DIM + n0;
#pragma unroll
        for (int fn = 0; fn < 2; ++fn)
          atomicAdd(orow + wn + fn * 16 + lr, wgt * acc[fm][fn][j]);
      }
    }
  }
}

// ---------------------------------------------------------------------------
extern "C" void kernel_launch(void* const* d_in, const int* in_sizes, int n_in,
                              void* d_out, int out_size, void* d_ws, size_t ws_size,
                              hipStream_t stream) {
  const float* x   = (const float*)d_in[0];
  const float* wg  = (const float*)d_in[1];
  const float* w13 = (const float*)d_in[2];
  const float* w2  = (const float*)d_in[3];
  float* out = (float*)d_out;

  char* ws = (char*)d_ws;
  int*   cnt    = (int*)(ws + 0);
  int*   cnt2   = (int*)(ws + 64);
  int*   off    = (int*)(ws + 128);
  int*   sel    = (int*)(ws + 1024);
  float* wt     = (float*)(ws + 1024 + 16384);
  int*   rowtok = (int*)(ws + 1024 + 32768);
  float* rowwt  = (float*)(ws + 1024 + 49152);
  size_t o = 128 * 1024;
  ushort* xhi = (ushort*)(ws + o); o += (size_t)T_TOK * DIM * 2;
  ushort* xlo = (ushort*)(ws + o); o += (size_t)T_TOK * DIM * 2;
  float*  H   = (float*)(ws + o);  o += (size_t)T_TOK * TOPK * 2 * FDIM * 4;
  ushort* ahi = (ushort*)(ws + o); o += (size_t)T_TOK * TOPK * FDIM * 2;
  ushort* alo = (ushort*)(ws + o); o += (size_t)T_TOK * TOPK * FDIM * 2;
  // total ws use ≈ 32.1 MB

  hipMemsetAsync(ws, 0, 256, stream);                              // cnt, cnt2
  hipMemsetAsync(d_out, 0, (size_t)out_size * sizeof(float), stream);

  router_k<<<T_TOK, 64, 0, stream>>>(x, wg, sel, wt, cnt);
  xsplit_k<<<(T_TOK * DIM) / 1024, 256, 0, stream>>>(x, xhi, xlo);
  offsets_k<<<1, 64, 0, stream>>>(cnt, off);
  fill_k<<<(T_TOK * TOPK + 255) / 256, 256, 0, stream>>>(sel, wt, off, cnt2, rowtok, rowwt);

  dim3 g1(2 * FDIM / BN, T_TOK / BM, NEXP);  // (16,16,16), most blocks early-exit
  gemm1_k<<<g1, 256, 0, stream>>>(xhi, xlo, w13, off, rowtok, H);

  act_k<<<(T_TOK * TOPK * FDIM) / 1024, 256, 0, stream>>>(H, ahi, alo);

  dim3 g2(DIM / BN, T_TOK / BM, NEXP);       // (16,16,16)
  gemm2_k<<<g2, 256, 0, stream>>>(ahi, alo, w2, off, rowtok, rowwt, out);
}

// Round 6
// 293.619 us; speedup vs baseline: 1.0937x; 1.0690x over previous
//
#include <hip/hip_runtime.h>
#include <hip/hip_bf16.h>
#include <math.h>

#define T_TOK 2048
#define DIM   1024
#define NEXP  16
#define FDIM  512
#define TOPK  2

#define BM 128
#define BN 64
#define BK 32

typedef float f32x4 __attribute__((ext_vector_type(4)));
typedef short s16x8 __attribute__((ext_vector_type(8)));

static __device__ __forceinline__ ushort f2bf(float f) {
  union { float f; unsigned u; } v; v.f = f;
  unsigned u = v.u;
  unsigned r = u + 0x7fffu + ((u >> 16) & 1u);  // round-to-nearest-even
  return (ushort)(r >> 16);
}
static __device__ __forceinline__ float bf2f(ushort h) {
  union { unsigned u; float f; } v; v.u = ((unsigned)h) << 16; return v.f;
}
static __device__ __forceinline__ void split2(float f, ushort& h, ushort& l) {
  ushort hb = f2bf(f);
  h = hb;
  l = f2bf(f - bf2f(hb));
}

// ---------------- Router: logits -> top-2 -> renormalized weights ----------
__global__ __launch_bounds__(64) void router_k(const float* __restrict__ x,
                                               const float* __restrict__ wg,
                                               int* __restrict__ sel,
                                               float* __restrict__ wt,
                                               int* __restrict__ cnt) {
  int t = blockIdx.x;
  int lane = threadIdx.x;
  const float* xr = x + (size_t)t * DIM;
  float acc[NEXP];
#pragma unroll
  for (int e = 0; e < NEXP; ++e) acc[e] = 0.f;
  for (int d0 = 0; d0 < DIM; d0 += 64) {
    float xv = xr[d0 + lane];
#pragma unroll
    for (int e = 0; e < NEXP; ++e) acc[e] += xv * wg[e * DIM + d0 + lane];
  }
#pragma unroll
  for (int e = 0; e < NEXP; ++e) {
    float v = acc[e];
    v += __shfl_xor(v, 32); v += __shfl_xor(v, 16); v += __shfl_xor(v, 8);
    v += __shfl_xor(v, 4);  v += __shfl_xor(v, 2);  v += __shfl_xor(v, 1);
    acc[e] = v;
  }
  if (lane == 0) {
    float b1 = -1e30f, b2 = -1e30f; int i1 = 0, i2 = 0;
#pragma unroll
    for (int e = 0; e < NEXP; ++e) {
      float v = acc[e];
      if (v > b1) { b2 = b1; i2 = i1; b1 = v; i1 = e; }
      else if (v > b2) { b2 = v; i2 = e; }
    }
    // NORM_TOPK: softmax denominator cancels -> w1 = 1/(1+exp(l2-l1))
    float r = expf(b2 - b1);
    float w2v = r / (1.f + r);
    float w1v = 1.f - w2v;
    sel[t * 2 + 0] = i1; sel[t * 2 + 1] = i2;
    wt[t * 2 + 0] = w1v; wt[t * 2 + 1] = w2v;
    atomicAdd(&cnt[i1], 1);
    atomicAdd(&cnt[i2], 1);
  }
}

// ---------------- X -> bf16 hi/lo planes -----------------------------------
__global__ __launch_bounds__(256) void xsplit_k(const float* __restrict__ x,
                                                ushort* __restrict__ xhi,
                                                ushort* __restrict__ xlo) {
  int idx = (blockIdx.x * 256 + threadIdx.x) * 4;
  float4 v = *(const float4*)(x + idx);
  ushort h0,h1,h2,h3,l0,l1,l2,l3;
  split2(v.x, h0, l0); split2(v.y, h1, l1);
  split2(v.z, h2, l2); split2(v.w, h3, l3);
  *(ushort4*)(xhi + idx) = make_ushort4(h0, h1, h2, h3);
  *(ushort4*)(xlo + idx) = make_ushort4(l0, l1, l2, l3);
}

// ---------------- exclusive prefix over expert counts ----------------------
__global__ void offsets_k(const int* __restrict__ cnt, int* __restrict__ off) {
  if (threadIdx.x == 0 && blockIdx.x == 0) {
    int s = 0;
#pragma unroll
    for (int e = 0; e < NEXP; ++e) { off[e] = s; s += cnt[e]; }
    off[NEXP] = s;  // == T_TOK*TOPK
  }
}

// ---------------- compact (token, weight) rows per expert ------------------
__global__ __launch_bounds__(256) void fill_k(const int* __restrict__ sel,
                                              const float* __restrict__ wt,
                                              const int* __restrict__ off,
                                              int* __restrict__ cnt2,
                                              int* __restrict__ rowtok,
                                              float* __restrict__ rowwt) {
  int i = blockIdx.x * 256 + threadIdx.x;
  if (i >= T_TOK * TOPK) return;
  int e = sel[i];
  int pos = off[e] + atomicAdd(&cnt2[e], 1);
  rowtok[pos] = i >> 1;
  rowwt[pos] = wt[i];
}

// --- 2-deep prefetched k-step, raw barriers + counted waits (T4) -----------
// RACE FIX vs round 3: __builtin_amdgcn_s_barrier() is IntrNoMem — NOT a
// compiler memory fence. LDS ops could legally cross it (and MFMAs+their
// lgkmcnt waits could sink past it, leaving ds_reads in flight when other
// waves overwrite LDS). Protocol now:
//   lgkmcnt(0)+["memory"]  -> my ds_reads COMPLETE  (ISA: waitcnt before
//   s_barrier               s_barrier on data dep)
//   sched_barrier(0)       -> nothing moves up across the barrier
//   ds_write / prefetch-issue
//   lgkmcnt(0)+["memory"]  -> my ds_writes complete
//   s_barrier; sched_barrier(0)
//   ds_read; MFMA
// vmcnt is never drained: global prefetch stays in flight across barriers.
#define DECL_SET(S) uint4 pAh0##S, pAl0##S, pAh1##S, pAl1##S; float4 pB0##S, pB1##S;

#define LOAD_SET(S, KB)                                                      \
  pAh0##S = *(const uint4*)(a0h + (KB)); pAl0##S = *(const uint4*)(a0l + (KB)); \
  pAh1##S = *(const uint4*)(a1h + (KB)); pAl1##S = *(const uint4*)(a1l + (KB)); \
  pB0##S = *(const float4*)(bsrc + (KB)); pB1##S = *(const float4*)(bsrc + (KB) + 4);

#define MOE_KSTEP(S, KS, NSv)                                                \
  do {                                                                       \
    asm volatile("s_waitcnt lgkmcnt(0)" ::: "memory"); /* reads complete */  \
    __builtin_amdgcn_s_barrier();            /* barrier 1: LDS reusable */   \
    __builtin_amdgcn_sched_barrier(0);                                       \
    *(uint4*)((char*)Ah + boA0) = pAh0##S;                                   \
    *(uint4*)((char*)Al + boA0) = pAl0##S;                                   \
    *(uint4*)((char*)Ah + boA1) = pAh1##S;                                   \
    *(uint4*)((char*)Al + boA1) = pAl1##S;                                   \
    {                                                                        \
      float fv[8] = {pB0##S.x, pB0##S.y, pB0##S.z, pB0##S.w,                 \
                     pB1##S.x, pB1##S.y, pB1##S.z, pB1##S.w};                \
      uint hp[4], lp[4];                                                     \
      _Pragma("unroll")                                                      \
      for (int j = 0; j < 4; ++j) {                                          \
        ushort ha, la, hb, lb;                                               \
        split2(fv[2 * j], ha, la);                                           \
        split2(fv[2 * j + 1], hb, lb);                                       \
        hp[j] = (uint)ha | ((uint)hb << 16);                                 \
        lp[j] = (uint)la | ((uint)lb << 16);                                 \
      }                                                                      \
      *(uint4*)((char*)Bh + boB) = make_uint4(hp[0], hp[1], hp[2], hp[3]);   \
      *(uint4*)((char*)Bl + boB) = make_uint4(lp[0], lp[1], lp[2], lp[3]);   \
    }                                                                        \
    if ((KS) + 2 < (NSv)) { int kb = ((KS) + 2) * BK; LOAD_SET(S, kb) }      \
    asm volatile("s_waitcnt lgkmcnt(0)" ::: "memory"); /* writes complete */ \
    __builtin_amdgcn_s_barrier();            /* barrier 2: writes visible */ \
    __builtin_amdgcn_sched_barrier(0);                                       \
    s16x8 ah[4], al[4], bh[2], bl[2];                                        \
    _Pragma("unroll")                                                        \
    for (int fm = 0; fm < 4; ++fm) {                                         \
      int row = wm + fm * 16 + lr;                                           \
      int bo = (row * 64 + lk * 16) ^ ((row & 7) << 4);                      \
      ah[fm] = *(const s16x8*)((char*)Ah + bo);                              \
      al[fm] = *(const s16x8*)((char*)Al + bo);                              \
    }                                                                        \
    _Pragma("unroll")                                                        \
    for (int fn = 0; fn < 2; ++fn) {                                         \
      int row = wn + fn * 16 + lr;                                           \
      int bo = (row * 64 + lk * 16) ^ ((row & 7) << 4);                      \
      bh[fn] = *(const s16x8*)((char*)Bh + bo);                              \
      bl[fn] = *(const s16x8*)((char*)Bl + bo);                              \
    }                                                                        \
    _Pragma("unroll")                                                        \
    for (int fm = 0; fm < 4; ++fm)                                           \
      _Pragma("unroll")                                                      \
      for (int fn = 0; fn < 2; ++fn) {                                       \
        acc[fm][fn] = __builtin_amdgcn_mfma_f32_16x16x32_bf16(ah[fm], bh[fn], acc[fm][fn], 0, 0, 0); \
        acc[fm][fn] = __builtin_amdgcn_mfma_f32_16x16x32_bf16(ah[fm], bl[fn], acc[fm][fn], 0, 0, 0); \
        acc[fm][fn] = __builtin_amdgcn_mfma_f32_16x16x32_bf16(al[fm], bh[fn], acc[fm][fn], 0, 0, 0); \
      }                                                                      \
  } while (0)

// ---------------- GEMM1: H[r][c] = sum_d X[tok(r)][d] * W13[e][c][d] -------
__global__ __launch_bounds__(256, 2) void gemm1_k(const ushort* __restrict__ xhi,
                                                  const ushort* __restrict__ xlo,
                                                  const float* __restrict__ w13,
                                                  const int* __restrict__ off,
                                                  const int* __restrict__ rowtok,
                                                  float* __restrict__ H) {
  int e = blockIdx.z;
  int rbeg = off[e];
  int rows = off[e + 1] - rbeg;
  int m0 = blockIdx.y * BM;
  if (m0 >= rows) return;
  int n0 = blockIdx.x * BN;

  __shared__ ushort Ah[BM * BK], Al[BM * BK], Bh[BN * BK], Bl[BN * BK];
  __shared__ int toksh[BM];

  int tid = threadIdx.x;
  if (tid < BM) {
    int r = m0 + tid;
    toksh[tid] = rowtok[rbeg + (r < rows ? r : rows - 1)];
  }
  __syncthreads();

  int srow = tid >> 2;   // 0..63
  int sc = tid & 3;      // k-chunk of 8 elems
  int tok0 = toksh[srow];
  int tok1 = toksh[srow + 64];
  const ushort* a0h = xhi + (size_t)tok0 * DIM + sc * 8;
  const ushort* a0l = xlo + (size_t)tok0 * DIM + sc * 8;
  const ushort* a1h = xhi + (size_t)tok1 * DIM + sc * 8;
  const ushort* a1l = xlo + (size_t)tok1 * DIM + sc * 8;
  const float*  bsrc = w13 + ((size_t)e * (2 * FDIM) + (n0 + srow)) * DIM + sc * 8;

  int boA0 = (srow * 64 + sc * 16) ^ ((srow & 7) << 4);
  int boA1 = ((srow + 64) * 64 + sc * 16) ^ ((srow & 7) << 4);
  int boB  = boA0;

  f32x4 acc[4][2];
#pragma unroll
  for (int a = 0; a < 4; ++a)
#pragma unroll
    for (int b = 0; b < 2; ++b) acc[a][b] = {0.f, 0.f, 0.f, 0.f};

  int lane = tid & 63;
  int w = tid >> 6;
  int wm = (w & 1) * 64, wn = (w >> 1) * 32;
  int lr = lane & 15, lk = lane >> 4;

  DECL_SET(_A) DECL_SET(_B)
  LOAD_SET(_A, 0)        // tile 0
  LOAD_SET(_B, BK)       // tile 1

  const int NS = DIM / BK;  // 32, even
  for (int ks = 0; ks < NS; ks += 2) {
    MOE_KSTEP(_A, ks, NS);
    MOE_KSTEP(_B, ks + 1, NS);
  }

  // epilogue: C/D layout col=lane&15, row=(lane>>4)*4+j  [m89/m91 verified]
#pragma unroll
  for (int fm = 0; fm < 4; ++fm) {
    int rloc = wm + fm * 16 + lk * 4;
#pragma unroll
    for (int j = 0; j < 4; ++j) {
      int row = rloc + j;
      if (m0 + row < rows) {
        size_t gr = (size_t)(rbeg + m0 + row) * (2 * FDIM);
#pragma unroll
        for (int fn = 0; fn < 2; ++fn)
          H[gr + n0 + wn + fn * 16 + lr] = acc[fm][fn][j];
      }
    }
  }
}

// ---------------- act = silu(gate)*up, stored as bf16 hi/lo ----------------
__global__ __launch_bounds__(256) void act_k(const float* __restrict__ H,
                                             ushort* __restrict__ ahi,
                                             ushort* __restrict__ alo) {
  int idx = (blockIdx.x * 256 + threadIdx.x) * 4;  // over 4096*512
  int r = idx >> 9;
  int f = idx & 511;
  const float* hrow = H + (size_t)r * (2 * FDIM);
  float4 g = *(const float4*)(hrow + f);
  float4 u = *(const float4*)(hrow + FDIM + f);
  float a0 = g.x / (1.f + expf(-g.x)) * u.x;
  float a1 = g.y / (1.f + expf(-g.y)) * u.y;
  float a2 = g.z / (1.f + expf(-g.z)) * u.z;
  float a3 = g.w / (1.f + expf(-g.w)) * u.w;
  ushort h0,h1,h2,h3,l0,l1,l2,l3;
  split2(a0, h0, l0); split2(a1, h1, l1);
  split2(a2, h2, l2); split2(a3, h3, l3);
  *(ushort4*)(ahi + (size_t)r * FDIM + f) = make_ushort4(h0, h1, h2, h3);
  *(ushort4*)(alo + (size_t)r * FDIM + f) = make_ushort4(l0, l1, l2, l3);
}

// ---------------- GEMM2: out[tok(r)][d] += w(r) * sum_f act[r][f]*W2[e][d][f]
__global__ __launch_bounds__(256, 2) void gemm2_k(const ushort* __restrict__ ahi,
                                                  const ushort* __restrict__ alo,
                                                  const float* __restrict__ w2,
                                                  const int* __restrict__ off,
                                                  const int* __restrict__ rowtok,
                                                  const float* __restrict__ rowwt,
                                                  float* __restrict__ out) {
  int e = blockIdx.z;
  int rbeg = off[e];
  int rows = off[e + 1] - rbeg;
  int m0 = blockIdx.y * BM;
  if (m0 >= rows) return;
  int n0 = blockIdx.x * BN;

  __shared__ ushort Ah[BM * BK], Al[BM * BK], Bh[BN * BK], Bl[BN * BK];
  __shared__ int toksh[BM];
  __shared__ float wtsh[BM];

  int tid = threadIdx.x;
  if (tid < BM) {
    int r = m0 + tid;
    int rr = rbeg + (r < rows ? r : rows - 1);
    toksh[tid] = rowtok[rr];
    wtsh[tid] = (r < rows) ? rowwt[rr] : 0.f;
  }
  __syncthreads();

  int srow = tid >> 2;
  int sc = tid & 3;
  int rg0 = m0 + srow;       rg0 = (rg0 < rows ? rg0 : rows - 1);
  int rg1 = m0 + srow + 64;  rg1 = (rg1 < rows ? rg1 : rows - 1);
  const ushort* a0h = ahi + (size_t)(rbeg + rg0) * FDIM + sc * 8;
  const ushort* a0l = alo + (size_t)(rbeg + rg0) * FDIM + sc * 8;
  const ushort* a1h = ahi + (size_t)(rbeg + rg1) * FDIM + sc * 8;
  const ushort* a1l = alo + (size_t)(rbeg + rg1) * FDIM + sc * 8;
  const float*  bsrc = w2 + ((size_t)e * DIM + (n0 + srow)) * FDIM + sc * 8;

  int boA0 = (srow * 64 + sc * 16) ^ ((srow & 7) << 4);
  int boA1 = ((srow + 64) * 64 + sc * 16) ^ ((srow & 7) << 4);
  int boB  = boA0;

  f32x4 acc[4][2];
#pragma unroll
  for (int a = 0; a < 4; ++a)
#pragma unroll
    for (int b = 0; b < 2; ++b) acc[a][b] = {0.f, 0.f, 0.f, 0.f};

  int lane = tid & 63;
  int w = tid >> 6;
  int wm = (w & 1) * 64, wn = (w >> 1) * 32;
  int lr = lane & 15, lk = lane >> 4;

  DECL_SET(_A) DECL_SET(_B)
  LOAD_SET(_A, 0)
  LOAD_SET(_B, BK)

  const int NS = FDIM / BK;  // 16, even
  for (int ks = 0; ks < NS; ks += 2) {
    MOE_KSTEP(_A, ks, NS);
    MOE_KSTEP(_B, ks + 1, NS);
  }

#pragma unroll
  for (int fm = 0; fm < 4; ++fm) {
    int rloc = wm + fm * 16 + lk * 4;
#pragma unroll
    for (int j = 0; j < 4; ++j) {
      int row = rloc + j;
      if (m0 + row < rows) {
        int tok = toksh[row];
        float wgt = wtsh[row];
        float* orow = out + (size_t)tok * DIM + n0;
#pragma unroll
        for (int fn = 0; fn < 2; ++fn)
          atomicAdd(orow + wn + fn * 16 + lr, wgt * acc[fm][fn][j]);
      }
    }
  }
}

// ---------------------------------------------------------------------------
extern "C" void kernel_launch(void* const* d_in, const int* in_sizes, int n_in,
                              void* d_out, int out_size, void* d_ws, size_t ws_size,
                              hipStream_t stream) {
  const float* x   = (const float*)d_in[0];
  const float* wg  = (const float*)d_in[1];
  const float* w13 = (const float*)d_in[2];
  const float* w2  = (const float*)d_in[3];
  float* out = (float*)d_out;

  char* ws = (char*)d_ws;
  int*   cnt    = (int*)(ws + 0);
  int*   cnt2   = (int*)(ws + 64);
  int*   off    = (int*)(ws + 128);
  int*   sel    = (int*)(ws + 1024);
  float* wt     = (float*)(ws + 1024 + 16384);
  int*   rowtok = (int*)(ws + 1024 + 32768);
  float* rowwt  = (float*)(ws + 1024 + 49152);
  size_t o = 128 * 1024;
  ushort* xhi = (ushort*)(ws + o); o += (size_t)T_TOK * DIM * 2;
  ushort* xlo = (ushort*)(ws + o); o += (size_t)T_TOK * DIM * 2;
  float*  H   = (float*)(ws + o);  o += (size_t)T_TOK * TOPK * 2 * FDIM * 4;
  ushort* ahi = (ushort*)(ws + o); o += (size_t)T_TOK * TOPK * FDIM * 2;
  ushort* alo = (ushort*)(ws + o); o += (size_t)T_TOK * TOPK * FDIM * 2;
  // total ws use ≈ 32.1 MB

  hipMemsetAsync(ws, 0, 256, stream);                              // cnt, cnt2
  hipMemsetAsync(d_out, 0, (size_t)out_size * sizeof(float), stream);

  router_k<<<T_TOK, 64, 0, stream>>>(x, wg, sel, wt, cnt);
  xsplit_k<<<(T_TOK * DIM) / 1024, 256, 0, stream>>>(x, xhi, xlo);
  offsets_k<<<1, 64, 0, stream>>>(cnt, off);
  fill_k<<<(T_TOK * TOPK + 255) / 256, 256, 0, stream>>>(sel, wt, off, cnt2, rowtok, rowwt);

  dim3 g1(2 * FDIM / BN, T_TOK / BM, NEXP);  // (16,16,16), most blocks early-exit
  gemm1_k<<<g1, 256, 0, stream>>>(xhi, xlo, w13, off, rowtok, H);

  act_k<<<(T_TOK * TOPK * FDIM) / 1024, 256, 0, stream>>>(H, ahi, alo);

  dim3 g2(DIM / BN, T_TOK / BM, NEXP);       // (16,16,16)
  gemm2_k<<<g2, 256, 0, stream>>>(ahi, alo, w2, off, rowtok, rowwt, out);
}